// Round 5
// baseline (425.517 us; speedup 1.0000x reference)
//
#include <hip/hip_runtime.h>
#include <cstdint>

#define TPB 256

constexpr int B_ = 8;
constexpr int A_ = 76725;
constexpr int C_ = 80;
constexpr int K_ = 200;
constexpr int CAP = 1024;          // per-(b,c) candidate list capacity (mean ~630, sd ~25)
constexpr int LCAP = 16;           // per-class per-block LDS staging (mean 2.1, Poisson)
constexpr int NBC = B_ * C_;       // 640 per-class tasks
constexpr int P_ = 16;             // final-topk partitions per batch
constexpr int SL_ = C_ * K_ / P_;  // 1000 entries per partition
constexpr float T0 = 0.4f;         // logit pre-filter (score ~0.60); fallback covers misses
constexpr float CONF_Tf = 0.05f;
constexpr float IOU_Tf = 0.5f;

// ---------- sortable key helpers: (score desc, index asc) ----------
__device__ inline uint64_t pack_key(float v, unsigned idx) {
  unsigned u = __float_as_uint(v);
  u = (u & 0x80000000u) ? ~u : (u | 0x80000000u);
  return ((uint64_t)u << 32) | (uint64_t)(0xFFFFFFFFu ^ idx);
}
__device__ inline float key_val(uint64_t k) {
  unsigned u = (unsigned)(k >> 32);
  u = (u & 0x80000000u) ? (u & 0x7FFFFFFFu) : ~u;
  return __uint_as_float(u);
}
__device__ inline unsigned key_idx(uint64_t k) { return 0xFFFFFFFFu ^ (unsigned)k; }

// ---------- radix-select: exact top-R (by u64 key) of act[0..n) into sel ----------
__device__ void radix_select(uint64_t* act, uint64_t* nxt, int n, int R,
                             uint64_t* sel, int* scnt, unsigned* hist,
                             int* s_d, int* s_ncnt) {
  int tid = threadIdx.x;
  if (tid == 0) *scnt = 0;
  __syncthreads();
  if (n <= R) {
    for (int i = tid; i < n; i += TPB) sel[i] = act[i];
    if (tid == 0) *scnt = n;
    __syncthreads();
    return;
  }
  int w = tid >> 6;
  for (int shift = 56; shift >= 0; shift -= 8) {
    for (int i = tid; i < 4 * 256; i += TPB) hist[i] = 0;
    __syncthreads();
    for (int i = tid; i < n; i += TPB)
      atomicAdd(&hist[(w << 8) + (int)((act[i] >> shift) & 255)], 1u);
    __syncthreads();
    if (tid < 256)
      hist[tid] = hist[tid] + hist[256 + tid] + hist[512 + tid] + hist[768 + tid];
    __syncthreads();
    for (int off = 1; off < 256; off <<= 1) {   // suffix sums: hist[t] = #digit >= t
      unsigned add = (tid < 256 && tid + off < 256) ? hist[tid + off] : 0u;
      __syncthreads();
      if (tid < 256) hist[tid] += add;
      __syncthreads();
    }
    if (tid < 256) {
      unsigned s = hist[tid];
      unsigned s1 = (tid == 255) ? 0u : hist[tid + 1];
      if ((int)s >= R && (int)s1 < R) *s_d = tid;
    }
    if (tid == 0) *s_ncnt = 0;
    __syncthreads();
    int d = *s_d;
    int above = (d == 255) ? 0 : (int)hist[d + 1];
    int cntd = (int)hist[d] - above;
    int need = R - above;
    if (need == cntd) {                // bin fits exactly: accept digit >= d, done
      for (int i = tid; i < n; i += TPB)
        if ((int)((act[i] >> shift) & 255) >= d) sel[atomicAdd(scnt, 1)] = act[i];
      __syncthreads();
      return;
    }
    if (cntd == n) { R = need; continue; }      // common-prefix pass: no copy
    for (int i = tid; i < n; i += TPB) {
      int dg = (int)((act[i] >> shift) & 255);
      if (dg > d) sel[atomicAdd(scnt, 1)] = act[i];
      else if (dg == d) nxt[atomicAdd(s_ncnt, 1)] = act[i];
    }
    __syncthreads();
    uint64_t* t = act; act = nxt; nxt = t;
    n = cntd; R = need;
  }
  for (int i = tid; i < R && i < n; i += TPB) sel[atomicAdd(scnt, 1)] = act[i];
  __syncthreads();
}

// ---------- hybrid bitonic sort of sel[0..256) descending, 1 elem/thread ----------
__device__ inline uint64_t shfl_xor_u64(uint64_t x, int m) {
  unsigned lo = (unsigned)__shfl_xor((int)(unsigned)x, m, 64);
  unsigned hi = (unsigned)__shfl_xor((int)(x >> 32), m, 64);
  return ((uint64_t)hi << 32) | lo;
}
__device__ void sort256_desc(uint64_t* sel) {
  int tid = threadIdx.x;
  uint64_t v = sel[tid];
  for (int k = 2; k <= 256; k <<= 1) {
    for (int j = k >> 1; j > 0; j >>= 1) {
      uint64_t other;
      if (j >= 64) {
        sel[tid] = v;
        __syncthreads();
        other = sel[tid ^ j];
        __syncthreads();
      } else {
        other = shfl_xor_u64(v, j);
      }
      bool up = ((tid & k) == 0);
      bool lower = ((tid & j) == 0);
      bool takeMax = (up == lower);
      bool sw = takeMax ? (other > v) : (other < v);
      v = sw ? other : v;
    }
  }
  sel[tid] = v;
  __syncthreads();
}

// ---------- legacy streaming top-200 (fallback path only) ----------
__device__ inline void bitonic_sort_desc_1024(uint64_t* buf, int tid) {
  for (int k = 2; k <= 1024; k <<= 1) {
    for (int j = k >> 1; j > 0; j >>= 1) {
      for (int i = tid; i < 1024; i += TPB) {
        int ixj = i ^ j;
        if (ixj > i) {
          uint64_t a = buf[i], b = buf[ixj];
          bool dir = ((i & k) == 0);
          if ((a < b) == dir) { buf[i] = b; buf[ixj] = a; }
        }
      }
      __syncthreads();
    }
  }
}
__device__ inline void compact_topk(uint64_t* buf, int* s_cnt, float* s_thr, int tid) {
  int cnt = *s_cnt;
  if (cnt > 1024) cnt = 1024;
  for (int i = cnt + tid; i < 1024; i += TPB) buf[i] = 0;
  __syncthreads();
  bitonic_sort_desc_1024(buf, tid);
  if (tid == 0) {
    *s_cnt = cnt < K_ ? cnt : K_;
    if (cnt >= K_) *s_thr = key_val(buf[K_ - 1]);
  }
  __syncthreads();
}
template <typename F>
__device__ inline void stream_topk(int n, F fetch, uint64_t* buf, int* s_cnt,
                                   float* s_thr, int tid) {
  for (int base = 0; base < n; base += TPB) {
    int i = base + tid;
    if (i < n) {
      uint64_t key; float v;
      fetch(i, key, v);
      if (v >= *s_thr) {
        int p = atomicAdd(s_cnt, 1);
        if (p < 1024) buf[p] = key;
      }
    }
    __syncthreads();
    int cur = *s_cnt;
    __syncthreads();
    if (cur >= 768) compact_topk(buf, s_cnt, s_thr, tid);
  }
  compact_topk(buf, s_cnt, s_thr, tid);
}

// ---------- K2: coalesced logit sweep; LDS-aggregated per-class scatter ----------
// 8 float4 loads in flight per thread; one global atomic per (block,class) at flush.
__global__ __launch_bounds__(TPB) void candidates_kernel(const float* __restrict__ logits,
                                                         uint64_t* __restrict__ lists,
                                                         int* __restrict__ cnts) {
  __shared__ uint64_t s_cand[C_][LCAP];          // 10 KB staging
  __shared__ int s_cnt[C_];
  constexpr int ANCH = 256;
  constexpr int nT = (A_ + ANCH - 1) / ANCH;
  int bb = blockIdx.x / nT, t = blockIdx.x - bb * nT;
  int a0 = t * ANCH;
  int na = min(ANCH, A_ - a0);
  int tid = threadIdx.x;
  for (int c = tid; c < C_; c += TPB) s_cnt[c] = 0;
  __syncthreads();

  const float4* src = (const float4*)(logits + ((size_t)bb * A_ + (size_t)a0) * C_);
  const int nq = na * (C_ / 4);                  // 5120 quads for a full tile
  for (int q0 = tid; q0 < nq; q0 += TPB * 8) {
    float4 v[8];
    int qv[8];
#pragma unroll
    for (int u = 0; u < 8; ++u) {                // 8 independent loads in flight (MLP)
      qv[u] = q0 + u * TPB;
      if (qv[u] < nq) v[u] = src[qv[u]];
    }
#pragma unroll
    for (int u = 0; u < 8; ++u) {
      int q = qv[u];
      if (q >= nq) continue;
      float lv[4] = {v[u].x, v[u].y, v[u].z, v[u].w};
      int pos = q * 4;
      int al = pos / C_;
      int c  = pos - al * C_;
#pragma unroll
      for (int j = 0; j < 4; ++j) {
        float l = lv[j];
        if (l > T0) {
          float s = 1.0f / (1.0f + expf(-l));    // bit-identical to prior rounds
          uint64_t key = pack_key(s, (unsigned)(a0 + al));
          int p = atomicAdd(&s_cnt[c + j], 1);   // LDS atomic: no vmcnt stall
          if (p < LCAP) {
            s_cand[c + j][p] = key;
          } else {                               // ~1e-10/block overflow: direct global
            int cc = bb * C_ + c + j;
            int g = atomicAdd(&cnts[cc * 16], 1);
            if (g < CAP) lists[(size_t)cc * CAP + g] = key;
          }
        }
      }
    }
  }
  __syncthreads();

  // flush: 80 lanes reserve in parallel (one latency per block), then copy
  if (tid < C_) {
    int n = min(s_cnt[tid], LCAP);
    if (n > 0) {
      int cc = bb * C_ + tid;
      int base = atomicAdd(&cnts[cc * 16], n);
      uint64_t* dst = lists + (size_t)cc * CAP;
      for (int j = 0; j < n; ++j) {
        int p = base + j;
        if (p < CAP) dst[p] = s_cand[tid][j];
      }
    }
  }
}

// ---------- K3: per-(b,c) exact top-200 (radix select) + inline decode + NMS ----------
__global__ __launch_bounds__(TPB) void class_nms_kernel(const float* __restrict__ logits,
                                                        const float4* __restrict__ regs,
                                                        const float4* __restrict__ anchors,
                                                        const uint64_t* __restrict__ lists,
                                                        const int* __restrict__ cnts,
                                                        float* __restrict__ cls_scores,
                                                        float4* __restrict__ cls_boxes) {
  __shared__ uint64_t s_bufA[1024];
  __shared__ uint64_t s_bufB[1024];
  __shared__ uint64_t s_sel[256];
  __shared__ unsigned s_hist[4 * 256];
  __shared__ int s_scnt, s_d, s_ncnt;
  __shared__ int s_cnt;
  __shared__ float s_thr;
  __shared__ float4 s_box[K_];
  __shared__ float s_score[K_], s_area[K_];
  __shared__ unsigned long long s_mask[K_][4];
  __shared__ unsigned long long s_keep[4];
  __shared__ unsigned long long s_conf[4];

  int tid = threadIdx.x;
  int cc = blockIdx.x;
  int bb = cc / C_, c = cc - bb * C_;
  int total = cnts[cc * 16];
  int m;

  if (total >= K_ && total <= CAP) {
    // main path: one contiguous gather + radix select + sort 256
    const uint64_t* lp = lists + (size_t)cc * CAP;
    for (int i = tid; i < total; i += TPB) s_bufA[i] = lp[i];
    __syncthreads();
    radix_select(s_bufA, s_bufB, total, K_, s_sel, &s_scnt, s_hist, &s_d, &s_ncnt);
    m = K_;
    if (tid >= m) s_sel[tid] = 0;
    __syncthreads();
    sort256_desc(s_sel);
  } else {
    // fallback (statistically never): full strided column rescan, legacy path
    if (tid == 0) { s_cnt = 0; s_thr = CONF_Tf; }
    __syncthreads();
    const float* col = logits + (size_t)bb * A_ * C_ + c;
    stream_topk(A_,
        [&](int i, uint64_t& key, float& v) {
          float l = col[(size_t)i * C_];
          v = 1.0f / (1.0f + expf(-l));
          key = pack_key(v, (unsigned)i);
        },
        s_bufA, &s_cnt, &s_thr, tid);
    m = s_cnt;
    s_sel[tid] = (tid < m) ? s_bufA[tid] : 0;
    __syncthreads();
  }

  // inline decode of survivor boxes (bit-identical to reference op sequence)
  if (tid < K_) {
    if (tid < m) {
      uint64_t key = s_sel[tid];
      unsigned a = key_idx(key);
      float4 r = regs[(size_t)bb * A_ + a];
      float4 an = anchors[a];
      float bxv = __fmul_rn(r.x, 0.1f), byv = __fmul_rn(r.y, 0.1f);
      float bwv = __fmul_rn(r.z, 0.2f), bhv = __fmul_rn(r.w, 0.2f);
      float cx = __fadd_rn(__fmul_rn(bxv, an.z), an.x);
      float cy = __fadd_rn(__fmul_rn(byv, an.w), an.y);
      float w  = __fmul_rn(expf(bwv), an.z);
      float h  = __fmul_rn(expf(bhv), an.w);
      float hw = __fmul_rn(w, 0.5f), hh = __fmul_rn(h, 0.5f);
      float4 bx = make_float4(__fsub_rn(cx, hw), __fsub_rn(cy, hh),
                              __fadd_rn(cx, hw), __fadd_rn(cy, hh));
      s_score[tid] = key_val(key);
      s_box[tid] = bx;
      s_area[tid] = __fmul_rn(__fsub_rn(bx.z, bx.x), __fsub_rn(bx.w, bx.y));
    } else {
      s_score[tid] = -1.0f;
      s_box[tid] = make_float4(0.f, 0.f, 0.f, 0.f);
      s_area[tid] = 0.f;
    }
  }
  // conf predicate ballot (wave w covers tids w*64..w*64+63)
  for (int i = tid; i < K_ * 4; i += TPB) ((unsigned long long*)s_mask)[i] = 0ull;
  __syncthreads();
  unsigned long long bal = __ballot(tid < K_ && s_score[tid] > CONF_Tf);
  if ((tid & 63) == 0) s_conf[tid >> 6] = bal;

  // suppression bitmask: 19900 ordered pairs (k>i) spread evenly over 256 threads
  constexpr int NP = K_ * (K_ - 1) / 2;
  for (int p = tid; p < NP; p += TPB) {
    int k = (int)((1.0f + sqrtf(1.0f + 8.0f * (float)p)) * 0.5f);
    while (k * (k - 1) / 2 > p) --k;             // integer-correct the sqrt seed
    while (k * (k + 1) / 2 <= p) ++k;
    int i = p - k * (k - 1) / 2;                 // 0 <= i < k < 200
    float4 bk = s_box[k], bi = s_box[i];
    float ix1 = fmaxf(bk.x, bi.x), iy1 = fmaxf(bk.y, bi.y);
    float ix2 = fminf(bk.z, bi.z), iy2 = fminf(bk.w, bi.w);
    float iw = fmaxf(__fsub_rn(ix2, ix1), 0.f);
    float ih = fmaxf(__fsub_rn(iy2, iy1), 0.f);
    float inter = __fmul_rn(iw, ih);
    float uni = __fsub_rn(__fadd_rn(s_area[k], s_area[i]), inter);
    float iou = inter / fmaxf(uni, 1e-8f);       // padded zero-boxes -> iou 0, no bit
    if (iou > IOU_Tf) atomicOr(&s_mask[k][i >> 6], 1ull << (i & 63));
  }
  __syncthreads();

  // greedy scan (equivalent to reference fori_loop)
  if (tid == 0) {
    unsigned long long k0 = 0, k1 = 0, k2 = 0, k3 = 0;
    unsigned long long c0 = s_conf[0], c1 = s_conf[1], c2 = s_conf[2], c3 = s_conf[3];
    for (int i = 0; i < m; ++i) {
      unsigned long long cw = (i < 64) ? c0 : (i < 128) ? c1 : (i < 192) ? c2 : c3;
      if ((cw >> (i & 63)) & 1ull) {
        bool sup = ((s_mask[i][0] & k0) | (s_mask[i][1] & k1) |
                    (s_mask[i][2] & k2) | (s_mask[i][3] & k3)) != 0ull;
        if (!sup) {
          if (i < 64)       k0 |= 1ull << i;
          else if (i < 128) k1 |= 1ull << (i - 64);
          else if (i < 192) k2 |= 1ull << (i - 128);
          else              k3 |= 1ull << (i - 192);
        }
      }
    }
    s_keep[0] = k0; s_keep[1] = k1; s_keep[2] = k2; s_keep[3] = k3;
  }
  __syncthreads();

  if (tid < K_) {
    bool kept = (tid < m) && ((s_keep[tid >> 6] >> (tid & 63)) & 1ull);
    size_t o = (size_t)cc * K_ + tid;
    cls_scores[o] = kept ? s_score[tid] : -1.0f;
    cls_boxes[o] = s_box[tid];
  }
}

// ---------- K4a: per-(batch,1/16) top-200 of 1000 scores (select only) ----------
__global__ __launch_bounds__(TPB) void part_topk_kernel(const float* __restrict__ cls_scores,
                                                        uint64_t* __restrict__ tmp) {
  __shared__ uint64_t bufA[SL_];
  __shared__ uint64_t bufB[SL_];
  __shared__ uint64_t sel[256];
  __shared__ unsigned hist[4 * 256];
  __shared__ int s_scnt, s_d, s_ncnt;
  int tid = threadIdx.x;
  int bb = blockIdx.x / P_, part = blockIdx.x - bb * P_;
  int f0 = part * SL_;
  const float* sc = cls_scores + (size_t)bb * C_ * K_ + f0;
  for (int i = tid; i < SL_; i += TPB) bufA[i] = pack_key(sc[i], (unsigned)(f0 + i));
  __syncthreads();
  radix_select(bufA, bufB, SL_, K_, sel, &s_scnt, hist, &s_d, &s_ncnt);
  if (tid < K_) tmp[(size_t)blockIdx.x * K_ + tid] = sel[tid];
}

// ---------- K4b: per-batch exact top-200 of 16x200 + sorted outputs ----------
__global__ __launch_bounds__(TPB) void final_topk_kernel(const float4* __restrict__ cls_boxes,
                                                         const uint64_t* __restrict__ tmp,
                                                         float* __restrict__ out) {
  constexpr int NF = P_ * K_;                    // 3200
  __shared__ uint64_t bufA[NF];
  __shared__ uint64_t bufB[NF];
  __shared__ uint64_t sel[256];
  __shared__ unsigned hist[4 * 256];
  __shared__ int s_scnt, s_d, s_ncnt, s_m;
  int tid = threadIdx.x;
  int bb = blockIdx.x;
  const uint64_t* tp = tmp + (size_t)bb * NF;
  for (int i = tid; i < NF; i += TPB) bufA[i] = tp[i];
  __syncthreads();
  radix_select(bufA, bufB, NF, K_, sel, &s_scnt, hist, &s_d, &s_ncnt);
  if (tid >= s_scnt) sel[tid] = 0;
  if (tid == 0) s_m = K_;
  __syncthreads();
  sort256_desc(sel);
  if (tid < K_) {
    float v = key_val(sel[tid]);
    if (!(v > 0.0f)) atomicMin(&s_m, tid);       // first non-positive => valid count
  }
  __syncthreads();
  int m = s_m;

  if (tid < K_) {
    float4 bx = make_float4(0.f, 0.f, 0.f, 0.f);
    float sv = 0.f, cv = 0.f;
    if (tid < m) {
      uint64_t key = sel[tid];
      unsigned f = key_idx(key);                 // flat index c*K_+rank within batch
      sv = key_val(key);
      cv = (float)(f / K_);
      bx = cls_boxes[(size_t)bb * C_ * K_ + f];
    }
    ((float4*)out)[(size_t)bb * K_ + tid] = bx;           // nmsed_boxes [8,200,4]
    out[B_ * K_ * 4 + bb * K_ + tid] = sv;                // nmsed_scores [8,200]
    out[B_ * K_ * 5 + bb * K_ + tid] = cv;                // nmsed_classes [8,200]
  }
  if (tid == 0) out[B_ * K_ * 6 + bb] = (float)m;          // valid [8] (as f32)
}

extern "C" void kernel_launch(void* const* d_in, const int* in_sizes, int n_in,
                              void* d_out, int out_size, void* d_ws, size_t ws_size,
                              hipStream_t stream) {
  const float* logits  = (const float*)d_in[0];   // [8,76725,80]
  const float4* regs   = (const float4*)d_in[1];  // [8,76725,4]
  const float4* anchors = (const float4*)d_in[2]; // [76725,4]
  float* out = (float*)d_out;

  char* ws = (char*)d_ws;
  uint64_t* lists    = (uint64_t*)ws;              size_t off = (size_t)NBC * CAP * 8;
  int* cnts          = (int*)(ws + off);           off += (size_t)NBC * 16 * 4;
  float* cls_scores  = (float*)(ws + off);         off += (size_t)NBC * K_ * 4;
  float4* cls_boxes  = (float4*)(ws + off);        off += (size_t)NBC * K_ * 16;
  uint64_t* tmp      = (uint64_t*)(ws + off);      // + 8*16*200*8 = total ~8.05 MB

  hipMemsetAsync(cnts, 0, (size_t)NBC * 16 * 4, stream);
  constexpr int nT = (A_ + 255) / 256;
  candidates_kernel<<<B_ * nT, TPB, 0, stream>>>(logits, lists, cnts);
  class_nms_kernel<<<NBC, TPB, 0, stream>>>(logits, regs, anchors, lists, cnts,
                                            cls_scores, cls_boxes);
  part_topk_kernel<<<B_ * P_, TPB, 0, stream>>>(cls_scores, tmp);
  final_topk_kernel<<<B_, TPB, 0, stream>>>(cls_boxes, tmp, out);
}

// Round 6
// 397.708 us; speedup vs baseline: 1.0699x; 1.0699x over previous
//
#include <hip/hip_runtime.h>
#include <cstdint>

#define TPB 256

constexpr int B_ = 8;
constexpr int A_ = 76725;
constexpr int C_ = 80;
constexpr int K_ = 200;
constexpr int CAP = 1024;          // per-(b,c) candidate list capacity (mean ~630, sd ~25)
constexpr int LCAP = 16;           // per-class per-block LDS staging (mean 2.1, Poisson)
constexpr int NBC = B_ * C_;       // 640 per-class tasks
constexpr int P_ = 16;             // final-topk partitions per batch
constexpr int SL_ = C_ * K_ / P_;  // 1000 entries per partition
constexpr float T0 = 0.4f;         // logit pre-filter (score ~0.60); fallback covers misses
constexpr float CONF_Tf = 0.05f;
constexpr float IOU_Tf = 0.5f;

typedef float float4v __attribute__((ext_vector_type(4)));

// ---------- sortable key helpers: (score desc, index asc) ----------
__device__ inline uint64_t pack_key(float v, unsigned idx) {
  unsigned u = __float_as_uint(v);
  u = (u & 0x80000000u) ? ~u : (u | 0x80000000u);
  return ((uint64_t)u << 32) | (uint64_t)(0xFFFFFFFFu ^ idx);
}
__device__ inline float key_val(uint64_t k) {
  unsigned u = (unsigned)(k >> 32);
  u = (u & 0x80000000u) ? (u & 0x7FFFFFFFu) : ~u;
  return __uint_as_float(u);
}
__device__ inline unsigned key_idx(uint64_t k) { return 0xFFFFFFFFu ^ (unsigned)k; }

// ---------- radix-select: exact top-R (by u64 key) of act[0..n) into sel ----------
__device__ void radix_select(uint64_t* act, uint64_t* nxt, int n, int R,
                             uint64_t* sel, int* scnt, unsigned* hist,
                             int* s_d, int* s_ncnt) {
  int tid = threadIdx.x;
  if (tid == 0) *scnt = 0;
  __syncthreads();
  if (n <= R) {
    for (int i = tid; i < n; i += TPB) sel[i] = act[i];
    if (tid == 0) *scnt = n;
    __syncthreads();
    return;
  }
  int w = tid >> 6;
  for (int shift = 56; shift >= 0; shift -= 8) {
    for (int i = tid; i < 4 * 256; i += TPB) hist[i] = 0;
    __syncthreads();
    for (int i = tid; i < n; i += TPB)
      atomicAdd(&hist[(w << 8) + (int)((act[i] >> shift) & 255)], 1u);
    __syncthreads();
    if (tid < 256)
      hist[tid] = hist[tid] + hist[256 + tid] + hist[512 + tid] + hist[768 + tid];
    __syncthreads();
    for (int off = 1; off < 256; off <<= 1) {   // suffix sums: hist[t] = #digit >= t
      unsigned add = (tid < 256 && tid + off < 256) ? hist[tid + off] : 0u;
      __syncthreads();
      if (tid < 256) hist[tid] += add;
      __syncthreads();
    }
    if (tid < 256) {
      unsigned s = hist[tid];
      unsigned s1 = (tid == 255) ? 0u : hist[tid + 1];
      if ((int)s >= R && (int)s1 < R) *s_d = tid;
    }
    if (tid == 0) *s_ncnt = 0;
    __syncthreads();
    int d = *s_d;
    int above = (d == 255) ? 0 : (int)hist[d + 1];
    int cntd = (int)hist[d] - above;
    int need = R - above;
    if (need == cntd) {                // bin fits exactly: accept digit >= d, done
      for (int i = tid; i < n; i += TPB)
        if ((int)((act[i] >> shift) & 255) >= d) sel[atomicAdd(scnt, 1)] = act[i];
      __syncthreads();
      return;
    }
    if (cntd == n) { R = need; continue; }      // common-prefix pass: no copy
    for (int i = tid; i < n; i += TPB) {
      int dg = (int)((act[i] >> shift) & 255);
      if (dg > d) sel[atomicAdd(scnt, 1)] = act[i];
      else if (dg == d) nxt[atomicAdd(s_ncnt, 1)] = act[i];
    }
    __syncthreads();
    uint64_t* t = act; act = nxt; nxt = t;
    n = cntd; R = need;
  }
  for (int i = tid; i < R && i < n; i += TPB) sel[atomicAdd(scnt, 1)] = act[i];
  __syncthreads();
}

// ---------- hybrid bitonic sort of sel[0..256) descending, 1 elem/thread ----------
__device__ inline uint64_t shfl_xor_u64(uint64_t x, int m) {
  unsigned lo = (unsigned)__shfl_xor((int)(unsigned)x, m, 64);
  unsigned hi = (unsigned)__shfl_xor((int)(x >> 32), m, 64);
  return ((uint64_t)hi << 32) | lo;
}
__device__ void sort256_desc(uint64_t* sel) {
  int tid = threadIdx.x;
  uint64_t v = sel[tid];
  for (int k = 2; k <= 256; k <<= 1) {
    for (int j = k >> 1; j > 0; j >>= 1) {
      uint64_t other;
      if (j >= 64) {
        sel[tid] = v;
        __syncthreads();
        other = sel[tid ^ j];
        __syncthreads();
      } else {
        other = shfl_xor_u64(v, j);
      }
      bool up = ((tid & k) == 0);
      bool lower = ((tid & j) == 0);
      bool takeMax = (up == lower);
      bool sw = takeMax ? (other > v) : (other < v);
      v = sw ? other : v;
    }
  }
  sel[tid] = v;
  __syncthreads();
}

// ---------- legacy streaming top-200 (fallback path only) ----------
__device__ inline void bitonic_sort_desc_1024(uint64_t* buf, int tid) {
  for (int k = 2; k <= 1024; k <<= 1) {
    for (int j = k >> 1; j > 0; j >>= 1) {
      for (int i = tid; i < 1024; i += TPB) {
        int ixj = i ^ j;
        if (ixj > i) {
          uint64_t a = buf[i], b = buf[ixj];
          bool dir = ((i & k) == 0);
          if ((a < b) == dir) { buf[i] = b; buf[ixj] = a; }
        }
      }
      __syncthreads();
    }
  }
}
__device__ inline void compact_topk(uint64_t* buf, int* s_cnt, float* s_thr, int tid) {
  int cnt = *s_cnt;
  if (cnt > 1024) cnt = 1024;
  for (int i = cnt + tid; i < 1024; i += TPB) buf[i] = 0;
  __syncthreads();
  bitonic_sort_desc_1024(buf, tid);
  if (tid == 0) {
    *s_cnt = cnt < K_ ? cnt : K_;
    if (cnt >= K_) *s_thr = key_val(buf[K_ - 1]);
  }
  __syncthreads();
}
template <typename F>
__device__ inline void stream_topk(int n, F fetch, uint64_t* buf, int* s_cnt,
                                   float* s_thr, int tid) {
  for (int base = 0; base < n; base += TPB) {
    int i = base + tid;
    if (i < n) {
      uint64_t key; float v;
      fetch(i, key, v);
      if (v >= *s_thr) {
        int p = atomicAdd(s_cnt, 1);
        if (p < 1024) buf[p] = key;
      }
    }
    __syncthreads();
    int cur = *s_cnt;
    __syncthreads();
    if (cur >= 768) compact_topk(buf, s_cnt, s_thr, tid);
  }
  compact_topk(buf, s_cnt, s_thr, tid);
}

// ---------- K2: coalesced logit sweep; LDS-aggregated per-class scatter ----------
// R4-proven config (4-deep MLP, nq%1024==0 on full tiles) + non-temporal stream loads.
__global__ __launch_bounds__(TPB) void candidates_kernel(const float* __restrict__ logits,
                                                         uint64_t* __restrict__ lists,
                                                         int* __restrict__ cnts) {
  __shared__ uint64_t s_cand[C_][LCAP];          // 10 KB staging
  __shared__ int s_cnt[C_];
  constexpr int ANCH = 256;
  constexpr int nT = (A_ + ANCH - 1) / ANCH;
  int bb = blockIdx.x / nT, t = blockIdx.x - bb * nT;
  int a0 = t * ANCH;
  int na = min(ANCH, A_ - a0);
  int tid = threadIdx.x;
  for (int c = tid; c < C_; c += TPB) s_cnt[c] = 0;
  __syncthreads();

  const float4v* src = (const float4v*)(logits + ((size_t)bb * A_ + (size_t)a0) * C_);
  const int nq = na * (C_ / 4);
  for (int q0 = tid; q0 < nq; q0 += TPB * 4) {
    float4v v[4];
    int qv[4] = {q0, q0 + TPB, q0 + 2 * TPB, q0 + 3 * TPB};
#pragma unroll
    for (int u = 0; u < 4; ++u)                  // independent nt loads in flight
      if (qv[u] < nq) v[u] = __builtin_nontemporal_load(src + qv[u]);
#pragma unroll
    for (int u = 0; u < 4; ++u) {
      int q = qv[u];
      if (q >= nq) continue;
      float lv[4] = {v[u].x, v[u].y, v[u].z, v[u].w};
      int pos = q * 4;
      int al = pos / C_;
      int c  = pos - al * C_;
#pragma unroll
      for (int j = 0; j < 4; ++j) {
        float l = lv[j];
        if (l > T0) {
          float s = 1.0f / (1.0f + expf(-l));    // bit-identical to prior rounds
          uint64_t key = pack_key(s, (unsigned)(a0 + al));
          int p = atomicAdd(&s_cnt[c + j], 1);   // LDS atomic: no vmcnt stall
          if (p < LCAP) {
            s_cand[c + j][p] = key;
          } else {                               // ~1e-10/block overflow: direct global
            int cc = bb * C_ + c + j;
            int g = atomicAdd(&cnts[cc * 16], 1);
            if (g < CAP) lists[(size_t)cc * CAP + g] = key;
          }
        }
      }
    }
  }
  __syncthreads();

  // flush: 80 lanes reserve in parallel (one latency per block), then copy
  if (tid < C_) {
    int n = min(s_cnt[tid], LCAP);
    if (n > 0) {
      int cc = bb * C_ + tid;
      int base = atomicAdd(&cnts[cc * 16], n);
      uint64_t* dst = lists + (size_t)cc * CAP;
      for (int j = 0; j < n; ++j) {
        int p = base + j;
        if (p < CAP) dst[p] = s_cand[tid][j];
      }
    }
  }
}

// ---------- K3: per-(b,c) exact top-200 (radix select) + inline decode + NMS ----------
__global__ __launch_bounds__(TPB) void class_nms_kernel(const float* __restrict__ logits,
                                                        const float4* __restrict__ regs,
                                                        const float4* __restrict__ anchors,
                                                        const uint64_t* __restrict__ lists,
                                                        const int* __restrict__ cnts,
                                                        float* __restrict__ cls_scores,
                                                        float4* __restrict__ cls_boxes) {
  __shared__ uint64_t s_bufA[1024];
  __shared__ uint64_t s_bufB[1024];
  __shared__ uint64_t s_sel[256];
  __shared__ unsigned s_hist[4 * 256];
  __shared__ int s_scnt, s_d, s_ncnt;
  __shared__ int s_cnt;
  __shared__ float s_thr;
  __shared__ float4 s_box[K_];
  __shared__ float s_score[K_], s_area[K_];
  __shared__ unsigned long long s_mask[K_][4];
  __shared__ unsigned long long s_keep[4];

  int tid = threadIdx.x;
  int cc = blockIdx.x;
  int bb = cc / C_, c = cc - bb * C_;
  int total = cnts[cc * 16];
  int m;

  if (total >= K_ && total <= CAP) {
    // main path: one contiguous gather + radix select + sort 256
    const uint64_t* lp = lists + (size_t)cc * CAP;
    for (int i = tid; i < total; i += TPB) s_bufA[i] = lp[i];
    __syncthreads();
    radix_select(s_bufA, s_bufB, total, K_, s_sel, &s_scnt, s_hist, &s_d, &s_ncnt);
    m = K_;
    if (tid >= m) s_sel[tid] = 0;
    __syncthreads();
    sort256_desc(s_sel);
  } else {
    // fallback (statistically never): full strided column rescan, legacy path
    if (tid == 0) { s_cnt = 0; s_thr = CONF_Tf; }
    __syncthreads();
    const float* col = logits + (size_t)bb * A_ * C_ + c;
    stream_topk(A_,
        [&](int i, uint64_t& key, float& v) {
          float l = col[(size_t)i * C_];
          v = 1.0f / (1.0f + expf(-l));
          key = pack_key(v, (unsigned)i);
        },
        s_bufA, &s_cnt, &s_thr, tid);
    m = s_cnt;
    s_sel[tid] = (tid < m) ? s_bufA[tid] : 0;
    __syncthreads();
  }

  // inline decode of survivor boxes (bit-identical to reference op sequence)
  if (tid < K_) {
    if (tid < m) {
      uint64_t key = s_sel[tid];
      unsigned a = key_idx(key);
      float4 r = regs[(size_t)bb * A_ + a];
      float4 an = anchors[a];
      float bxv = __fmul_rn(r.x, 0.1f), byv = __fmul_rn(r.y, 0.1f);
      float bwv = __fmul_rn(r.z, 0.2f), bhv = __fmul_rn(r.w, 0.2f);
      float cx = __fadd_rn(__fmul_rn(bxv, an.z), an.x);
      float cy = __fadd_rn(__fmul_rn(byv, an.w), an.y);
      float w  = __fmul_rn(expf(bwv), an.z);
      float h  = __fmul_rn(expf(bhv), an.w);
      float hw = __fmul_rn(w, 0.5f), hh = __fmul_rn(h, 0.5f);
      float4 bx = make_float4(__fsub_rn(cx, hw), __fsub_rn(cy, hh),
                              __fadd_rn(cx, hw), __fadd_rn(cy, hh));
      s_score[tid] = key_val(key);
      s_box[tid] = bx;
      s_area[tid] = __fmul_rn(__fsub_rn(bx.z, bx.x), __fsub_rn(bx.w, bx.y));
    } else {
      s_score[tid] = -1.0f;
      s_box[tid] = make_float4(0.f, 0.f, 0.f, 0.f);
      s_area[tid] = 0.f;
    }
  }
  __syncthreads();

  // suppression bitmask: thread k vs all i<k (R4-proven triangular form)
  if (tid < K_) {
    float4 bk = s_box[tid];
    float ak = s_area[tid];
    unsigned long long mw[4] = {0ull, 0ull, 0ull, 0ull};
    for (int i = 0; i < tid; ++i) {
      float4 bi = s_box[i];
      float ix1 = fmaxf(bk.x, bi.x), iy1 = fmaxf(bk.y, bi.y);
      float ix2 = fminf(bk.z, bi.z), iy2 = fminf(bk.w, bi.w);
      float iw = fmaxf(__fsub_rn(ix2, ix1), 0.f);
      float ih = fmaxf(__fsub_rn(iy2, iy1), 0.f);
      float inter = __fmul_rn(iw, ih);
      float uni = __fsub_rn(__fadd_rn(ak, s_area[i]), inter);
      float iou = inter / fmaxf(uni, 1e-8f);
      if (iou > IOU_Tf) mw[i >> 6] |= (1ull << (i & 63));
    }
    s_mask[tid][0] = mw[0]; s_mask[tid][1] = mw[1];
    s_mask[tid][2] = mw[2]; s_mask[tid][3] = mw[3];
  }
  __syncthreads();

  // greedy scan (equivalent to reference fori_loop)
  if (tid == 0) {
    unsigned long long k0 = 0, k1 = 0, k2 = 0, k3 = 0;
    for (int i = 0; i < m; ++i) {
      if (s_score[i] > CONF_Tf) {
        bool sup = ((s_mask[i][0] & k0) | (s_mask[i][1] & k1) |
                    (s_mask[i][2] & k2) | (s_mask[i][3] & k3)) != 0ull;
        if (!sup) {
          if (i < 64)       k0 |= 1ull << i;
          else if (i < 128) k1 |= 1ull << (i - 64);
          else if (i < 192) k2 |= 1ull << (i - 128);
          else              k3 |= 1ull << (i - 192);
        }
      }
    }
    s_keep[0] = k0; s_keep[1] = k1; s_keep[2] = k2; s_keep[3] = k3;
  }
  __syncthreads();

  if (tid < K_) {
    bool kept = (tid < m) && ((s_keep[tid >> 6] >> (tid & 63)) & 1ull);
    size_t o = (size_t)cc * K_ + tid;
    cls_scores[o] = kept ? s_score[tid] : -1.0f;
    cls_boxes[o] = s_box[tid];
  }
}

// ---------- K4a: per-(batch,1/16) top-200 of 1000 scores (select only) ----------
__global__ __launch_bounds__(TPB) void part_topk_kernel(const float* __restrict__ cls_scores,
                                                        uint64_t* __restrict__ tmp) {
  __shared__ uint64_t bufA[SL_];
  __shared__ uint64_t bufB[SL_];
  __shared__ uint64_t sel[256];
  __shared__ unsigned hist[4 * 256];
  __shared__ int s_scnt, s_d, s_ncnt;
  int tid = threadIdx.x;
  int bb = blockIdx.x / P_, part = blockIdx.x - bb * P_;
  int f0 = part * SL_;
  const float* sc = cls_scores + (size_t)bb * C_ * K_ + f0;
  for (int i = tid; i < SL_; i += TPB) bufA[i] = pack_key(sc[i], (unsigned)(f0 + i));
  __syncthreads();
  radix_select(bufA, bufB, SL_, K_, sel, &s_scnt, hist, &s_d, &s_ncnt);
  if (tid < K_) tmp[(size_t)blockIdx.x * K_ + tid] = sel[tid];
}

// ---------- K4b: per-batch exact top-200 of 16x200 + sorted outputs ----------
__global__ __launch_bounds__(TPB) void final_topk_kernel(const float4* __restrict__ cls_boxes,
                                                         const uint64_t* __restrict__ tmp,
                                                         float* __restrict__ out) {
  constexpr int NF = P_ * K_;                    // 3200
  __shared__ uint64_t bufA[NF];
  __shared__ uint64_t bufB[NF];
  __shared__ uint64_t sel[256];
  __shared__ unsigned hist[4 * 256];
  __shared__ int s_scnt, s_d, s_ncnt, s_m;
  int tid = threadIdx.x;
  int bb = blockIdx.x;
  const uint64_t* tp = tmp + (size_t)bb * NF;
  for (int i = tid; i < NF; i += TPB) bufA[i] = tp[i];
  __syncthreads();
  radix_select(bufA, bufB, NF, K_, sel, &s_scnt, hist, &s_d, &s_ncnt);
  if (tid >= s_scnt) sel[tid] = 0;
  if (tid == 0) s_m = K_;
  __syncthreads();
  sort256_desc(sel);
  if (tid < K_) {
    float v = key_val(sel[tid]);
    if (!(v > 0.0f)) atomicMin(&s_m, tid);       // first non-positive => valid count
  }
  __syncthreads();
  int m = s_m;

  if (tid < K_) {
    float4 bx = make_float4(0.f, 0.f, 0.f, 0.f);
    float sv = 0.f, cv = 0.f;
    if (tid < m) {
      uint64_t key = sel[tid];
      unsigned f = key_idx(key);                 // flat index c*K_+rank within batch
      sv = key_val(key);
      cv = (float)(f / K_);
      bx = cls_boxes[(size_t)bb * C_ * K_ + f];
    }
    ((float4*)out)[(size_t)bb * K_ + tid] = bx;           // nmsed_boxes [8,200,4]
    out[B_ * K_ * 4 + bb * K_ + tid] = sv;                // nmsed_scores [8,200]
    out[B_ * K_ * 5 + bb * K_ + tid] = cv;                // nmsed_classes [8,200]
  }
  if (tid == 0) out[B_ * K_ * 6 + bb] = (float)m;          // valid [8] (as f32)
}

extern "C" void kernel_launch(void* const* d_in, const int* in_sizes, int n_in,
                              void* d_out, int out_size, void* d_ws, size_t ws_size,
                              hipStream_t stream) {
  const float* logits  = (const float*)d_in[0];   // [8,76725,80]
  const float4* regs   = (const float4*)d_in[1];  // [8,76725,4]
  const float4* anchors = (const float4*)d_in[2]; // [76725,4]
  float* out = (float*)d_out;

  char* ws = (char*)d_ws;
  uint64_t* lists    = (uint64_t*)ws;              size_t off = (size_t)NBC * CAP * 8;
  int* cnts          = (int*)(ws + off);           off += (size_t)NBC * 16 * 4;
  float* cls_scores  = (float*)(ws + off);         off += (size_t)NBC * K_ * 4;
  float4* cls_boxes  = (float4*)(ws + off);        off += (size_t)NBC * K_ * 16;
  uint64_t* tmp      = (uint64_t*)(ws + off);      // + 8*16*200*8 = total ~8.05 MB

  hipMemsetAsync(cnts, 0, (size_t)NBC * 16 * 4, stream);
  constexpr int nT = (A_ + 255) / 256;
  candidates_kernel<<<B_ * nT, TPB, 0, stream>>>(logits, lists, cnts);
  class_nms_kernel<<<NBC, TPB, 0, stream>>>(logits, regs, anchors, lists, cnts,
                                            cls_scores, cls_boxes);
  part_topk_kernel<<<B_ * P_, TPB, 0, stream>>>(cls_scores, tmp);
  final_topk_kernel<<<B_, TPB, 0, stream>>>(cls_boxes, tmp, out);
}